// Round 4
// baseline (206.353 us; speedup 1.0000x reference)
//
#include <hip/hip_runtime.h>
#include <math.h>

#define NB 2
#define NT 4096
#define NC 512
#define NH 8
#define ND 64
#define N3C (3*NC)

typedef __attribute__((ext_vector_type(8))) __bf16 bf16x8;
typedef __attribute__((ext_vector_type(4))) __bf16 bf16x4;
typedef __attribute__((ext_vector_type(4))) float  f32x4;

// async 16B/lane global->LDS DMA; lds base must be wave-uniform
__device__ __forceinline__ void load_lds16(const __bf16* g, __bf16* l) {
    __builtin_amdgcn_global_load_lds(
        (const __attribute__((address_space(1))) void*)g,
        (__attribute__((address_space(3))) void*)l, 16, 0, 0);
}

// ---------------------------------------------------------------------------
// fp32 -> bf16 elementwise (x)
// ---------------------------------------------------------------------------
__global__ __launch_bounds__(256) void cvt_bf16_kernel(
    const float* __restrict__ x, __bf16* __restrict__ xb, int n)
{
    const int i = (blockIdx.x * 256 + threadIdx.x) << 3;
    if (i < n) {
        float4 a = *(const float4*)(x + i);
        float4 b = *(const float4*)(x + i + 4);
        bf16x8 o;
        o[0] = (__bf16)a.x; o[1] = (__bf16)a.y; o[2] = (__bf16)a.z; o[3] = (__bf16)a.w;
        o[4] = (__bf16)b.x; o[5] = (__bf16)b.y; o[6] = (__bf16)b.z; o[7] = (__bf16)b.w;
        *(bf16x8*)(xb + i) = o;
    }
}

// ---------------------------------------------------------------------------
// prep: W[K][N] fp32 -> Wt[N][K] bf16, both weights in one launch
// ---------------------------------------------------------------------------
__global__ __launch_bounds__(256) void prep_kernel(
    const float* __restrict__ Wqkv, const float* __restrict__ Wproj,
    __bf16* __restrict__ wqkvt, __bf16* __restrict__ wprojt)
{
    __shared__ float T[64][65];
    int id = blockIdx.x;
    const float* W; __bf16* Wt; int N, n0, k0;
    if (id < 192) { W = Wqkv;  Wt = wqkvt;  N = N3C; n0 = (id % 24) << 6; k0 = (id / 24) << 6; }
    else { id -= 192; W = Wproj; Wt = wprojt; N = NC;  n0 = (id & 7) << 6;  k0 = (id >> 3) << 6; }
    const int K = NC;

    const int tx = threadIdx.x & 15, ty = threadIdx.x >> 4;
#pragma unroll
    for (int i = 0; i < 4; ++i) {
        const int r = ty + (i << 4);
        float4 v = *(const float4*)(W + (size_t)(k0 + r) * N + n0 + (tx << 2));
        T[r][(tx << 2) + 0] = v.x;
        T[r][(tx << 2) + 1] = v.y;
        T[r][(tx << 2) + 2] = v.z;
        T[r][(tx << 2) + 3] = v.w;
    }
    __syncthreads();
#pragma unroll
    for (int i = 0; i < 4; ++i) {
        const int nr = ty + (i << 4);
        bf16x4 o;
        o[0] = (__bf16)T[(tx << 2) + 0][nr];
        o[1] = (__bf16)T[(tx << 2) + 1][nr];
        o[2] = (__bf16)T[(tx << 2) + 2][nr];
        o[3] = (__bf16)T[(tx << 2) + 3][nr];
        *(bf16x4*)(Wt + (size_t)(n0 + nr) * K + k0 + (tx << 2)) = o;
    }
}

// ---------------------------------------------------------------------------
// bf16 MFMA GEMM with global_load_lds staging. C = A @ Bt^T + bias.
// ---------------------------------------------------------------------------
template<int BM>
__global__ __launch_bounds__(256) void gemm_glds_kernel(
    const __bf16* __restrict__ A, const __bf16* __restrict__ Bt,
    const float* __restrict__ bias, void* __restrict__ Cout,
    int M, int N, int K, int out_bf16)
{
    constexpr int IT = BM / 32;              // i-tiles per wave (4 or 2)
    constexpr int AI = BM / 32;              // A DMA instrs per wave (4 or 2)
    __shared__ __align__(16) __bf16 As[BM * 64];
    __shared__ __align__(16) __bf16 Bs[128 * 64];

    const int tid  = threadIdx.x;
    const int w    = tid >> 6, lane = tid & 63;
    const int g    = lane >> 4, n = lane & 15;
    const int n7   = n & 7;
    const int wr   = (w >> 1) * (BM / 2);
    const int wc   = (w & 1) << 6;
    const int m0   = blockIdx.y * BM, n0 = blockIdx.x << 7;

    const __bf16* ag[AI]; __bf16* al[AI];
#pragma unroll
    for (int q = 0; q < AI; ++q) {
        const int G = w * (BM * 2) + q * 64 + lane;
        const int r = G >> 3, pg = G & 7, kg = pg ^ (r & 7);
        ag[q] = A + (size_t)(m0 + r) * K + (kg << 3);
        al[q] = As + ((w * (BM * 2) + q * 64) << 3);
    }
    const __bf16* bg[4]; __bf16* bl[4];
#pragma unroll
    for (int q = 0; q < 4; ++q) {
        const int G = w * 256 + q * 64 + lane;
        const int r = G >> 3, pg = G & 7, kg = pg ^ (r & 7);
        bg[q] = Bt + (size_t)(n0 + r) * K + (kg << 3);
        bl[q] = Bs + ((w * 256 + q * 64) << 3);
    }

    f32x4 acc[IT][4];
#pragma unroll
    for (int i = 0; i < IT; ++i)
#pragma unroll
        for (int j = 0; j < 4; ++j) acc[i][j] = (f32x4){0.f, 0.f, 0.f, 0.f};

    const int ksteps = K >> 6;
    for (int ks = 0; ks < ksteps; ++ks) {
        __syncthreads();
        const int ko = ks << 6;
#pragma unroll
        for (int q = 0; q < AI; ++q) load_lds16(ag[q] + ko, al[q]);
#pragma unroll
        for (int q = 0; q < 4;  ++q) load_lds16(bg[q] + ko, bl[q]);
        __syncthreads();

#pragma unroll
        for (int s = 0; s < 2; ++s) {
            bf16x8 af[IT], bf[4];
#pragma unroll
            for (int i = 0; i < IT; ++i) {
                const int row = wr + (i << 4) + n;
                af[i] = *(const bf16x8*)&As[(row << 6) + ((((s << 2) + g) ^ n7) << 3)];
            }
#pragma unroll
            for (int j = 0; j < 4; ++j) {
                const int row = wc + (j << 4) + n;
                bf[j] = *(const bf16x8*)&Bs[(row << 6) + ((((s << 2) + g) ^ n7) << 3)];
            }
#pragma unroll
            for (int i = 0; i < IT; ++i)
#pragma unroll
                for (int j = 0; j < 4; ++j)
                    acc[i][j] = __builtin_amdgcn_mfma_f32_16x16x32_bf16(af[i], bf[j], acc[i][j], 0, 0, 0);
        }
    }

#pragma unroll
    for (int j = 0; j < 4; ++j) {
        const int colg = n0 + wc + (j << 4) + n;
        const float bb = bias[colg];
#pragma unroll
        for (int i = 0; i < IT; ++i) {
#pragma unroll
            for (int reg = 0; reg < 4; ++reg) {
                const int rowg = m0 + wr + (i << 4) + (g << 2) + reg;
                const float v = acc[i][j][reg] + bb;
                if (out_bf16)
                    ((__bf16*)Cout)[(size_t)rowg * N + colg] = (__bf16)v;
                else
                    ((float*)Cout)[(size_t)rowg * N + colg] = v;
            }
        }
    }
}

// ---------------------------------------------------------------------------
// Causal flash attention, 4-wave (256-thread) blocks on 64-row Q tiles.
// Rationale (R3): regs ~100/thread (60 VGPR + 40 AGPR) cap the CU at 20
// waves; 8-wave blocks quantize that to TWO independent barrier domains ->
// ~47% issue utilization, invariant under split-K. 4-wave blocks give 4-5
// independent domains at the same wave count.
// mono==1: one block per (b,h,64-row qtile), bf16 out directly.
// mono==0: split-K, np=(m>>4)+1 parts (<=16 ktiles each), unnormalized
//          O (f32) + L to workspace; combine_kernel finishes.
// ---------------------------------------------------------------------------
__global__ __launch_bounds__(256, 4) void attn_kernel(
    const __bf16* __restrict__ qkv, int mono, __bf16* __restrict__ outb,
    float* __restrict__ Opart, float* __restrict__ Lpart)
{
    __shared__ __align__(16) unsigned char SMEM[27648];
    __bf16 (*QPs)[72] = (__bf16(*)[72])SMEM;
    __bf16 (*Ks)[72]  = (__bf16(*)[72])(SMEM + 9216);
    __bf16 (*Vt)[72]  = (__bf16(*)[72])(SMEM + 18432);

    const int tid  = threadIdx.x;
    const int xi   = blockIdx.x;
    const int bh   = blockIdx.y;
    const int b    = bh >> 3, h = bh & 7;

    int m, jt0, jt1, pid;
    if (mono) {
        m = (bh < 8) ? (63 - xi) : xi;
        jt0 = 0; jt1 = m + 1; pid = 0;
    } else {
        const int a  = (xi < 16) ? 0 : ((xi < 48) ? 1 : ((xi < 96) ? 2 : 3));
        const int np = a + 1;
        const int off = xi - 8 * a * (a + 1);
        m = (a << 4) + off / np;
        const int p  = off % np;
        const int ntk = m + 1;
        const int chunk = ntk / np, rem = ntk % np;
        jt0 = p * chunk + (p < rem ? p : rem);
        jt1 = jt0 + chunk + (p < rem ? 1 : 0);
        pid = bh * 160 + xi;
    }

    const int qr0  = m << 6;
    const size_t base = (size_t)b * NT * N3C;
    const int col  = h * ND;

    const int w    = tid >> 6;          // 0..3
    const int lane = tid & 63;
    const int g    = lane >> 4;
    const int n    = lane & 15;
    const int qg   = w >> 1;            // 2 q-groups of 32 rows
    const int kh   = w & 1;             // 2 k-halves of 32 cols
    const int qrow0 = qg << 5;
    const int kcol0 = kh << 5;
    const int sw   = (g ^ (n >> 2)) << 3;

    const int kr = tid >> 3;            // 0..31
    const int kc = (tid & 7) << 3;
    const int vd = lane;                // 0..63 (d index)
    const int vk = w << 3;              // 8 k-rows per wave group

    const __bf16* kptr = qkv + base + NC + col + kc;
    const __bf16* vptr = qkv + base + 2 * NC + col + vd;

    // Q load + scale (64 rows)
#pragma unroll
    for (int i = 0; i < 2; ++i) {
        const int r = kr + (i << 5);
        bf16x8 v = *(const bf16x8*)(qkv + base + (size_t)(qr0 + r) * N3C + col + kc);
        bf16x8 q;
#pragma unroll
        for (int j = 0; j < 8; ++j) q[j] = (__bf16)(0.125f * (float)v[j]);
        *(bf16x8*)&QPs[r][kc] = q;
    }
    __syncthreads();

    bf16x8 qf[2][2];
#pragma unroll
    for (int qt = 0; qt < 2; ++qt)
#pragma unroll
        for (int hh = 0; hh < 2; ++hh)
            qf[qt][hh] = *(const bf16x8*)&QPs[qrow0 + (qt << 4) + n][(hh << 5) + (g << 3)];

    bf16x8 ones;
#pragma unroll
    for (int j = 0; j < 8; ++j) ones[j] = (__bf16)1.0f;

    f32x4 O[2][4];
#pragma unroll
    for (int qt = 0; qt < 2; ++qt)
#pragma unroll
        for (int dt = 0; dt < 4; ++dt) O[qt][dt] = (f32x4){0.f, 0.f, 0.f, 0.f};
    f32x4 L[2] = {{0.f,0.f,0.f,0.f},{0.f,0.f,0.f,0.f}};

    // prefetch first K/V tile
    const int r0 = jt0 << 6;
    bf16x8 kreg[2];
#pragma unroll
    for (int i = 0; i < 2; ++i)
        kreg[i] = *(const bf16x8*)(kptr + (size_t)(r0 + kr + (i << 5)) * N3C);
    __bf16 vreg[16];
#pragma unroll
    for (int j = 0; j < 8; ++j) {
        vreg[j]     = vptr[(size_t)(r0 + vk + j) * N3C];
        vreg[8 + j] = vptr[(size_t)(r0 + vk + 32 + j) * N3C];
    }

    for (int jt = jt0; jt < jt1; ++jt) {
        __syncthreads();
#pragma unroll
        for (int i = 0; i < 2; ++i)
            *(bf16x8*)&Ks[kr + (i << 5)][kc] = kreg[i];
        {
            bf16x8 va, vb;
#pragma unroll
            for (int j = 0; j < 8; ++j) { va[j] = vreg[j]; vb[j] = vreg[8 + j]; }
            *(bf16x8*)&Vt[vd][vk]      = va;
            *(bf16x8*)&Vt[vd][vk + 32] = vb;
        }
        __syncthreads();

        if (jt + 1 < jt1) {
            const int kr1 = (jt + 1) << 6;
#pragma unroll
            for (int i = 0; i < 2; ++i)
                kreg[i] = *(const bf16x8*)(kptr + (size_t)(kr1 + kr + (i << 5)) * N3C);
#pragma unroll
            for (int j = 0; j < 8; ++j) {
                vreg[j]     = vptr[(size_t)(kr1 + vk + j) * N3C];
                vreg[8 + j] = vptr[(size_t)(kr1 + vk + 32 + j) * N3C];
            }
        }

        f32x4 S[2][2];
        __builtin_amdgcn_s_setprio(1);
#pragma unroll
        for (int t = 0; t < 2; ++t) {
            const bf16x8 k0 = *(const bf16x8*)&Ks[kcol0 + (t << 4) + n][(g << 3)];
            const bf16x8 k1 = *(const bf16x8*)&Ks[kcol0 + (t << 4) + n][32 + (g << 3)];
#pragma unroll
            for (int qt = 0; qt < 2; ++qt) {
                f32x4 a = {0.f, 0.f, 0.f, 0.f};
                a = __builtin_amdgcn_mfma_f32_16x16x32_bf16(qf[qt][0], k0, a, 0, 0, 0);
                a = __builtin_amdgcn_mfma_f32_16x16x32_bf16(qf[qt][1], k1, a, 0, 0, 0);
                S[qt][t] = a;
            }
        }
        __builtin_amdgcn_s_setprio(0);

        if (jt == m) {   // diagonal tile: causal mask
#pragma unroll
            for (int qt = 0; qt < 2; ++qt)
#pragma unroll
                for (int t = 0; t < 2; ++t)
#pragma unroll
                    for (int reg = 0; reg < 4; ++reg) {
                        const int kg = (jt << 6) + kcol0 + (t << 4) + n;
                        const int qgl = qr0 + qrow0 + (qt << 4) + (g << 2) + reg;
                        if (kg > qgl) S[qt][t][reg] = -INFINITY;
                    }
        }

#pragma unroll
        for (int qt = 0; qt < 2; ++qt)
#pragma unroll
            for (int t = 0; t < 2; ++t)
#pragma unroll
                for (int reg = 0; reg < 4; ++reg)
                    QPs[qrow0 + (qt << 4) + (g << 2) + reg]
                       [kcol0 + (((t << 4) + n) ^ (g << 3))] =
                        (__bf16)__expf(S[qt][t][reg]);

        bf16x8 vf[4];
#pragma unroll
        for (int dt = 0; dt < 4; ++dt) {
            const int vr = (dt << 4) + n;
            vf[dt] = *(const bf16x8*)&Vt[vr][kcol0 + (g << 3)];
        }

        __builtin_amdgcn_s_setprio(1);
#pragma unroll
        for (int qt = 0; qt < 2; ++qt) {
            const bf16x8 p = *(const bf16x8*)&QPs[qrow0 + (qt << 4) + n][kcol0 + sw];
            L[qt] = __builtin_amdgcn_mfma_f32_16x16x32_bf16(p, ones, L[qt], 0, 0, 0);
#pragma unroll
            for (int dt = 0; dt < 4; ++dt)
                O[qt][dt] = __builtin_amdgcn_mfma_f32_16x16x32_bf16(p, vf[dt], O[qt][dt], 0, 0, 0);
        }
        __builtin_amdgcn_s_setprio(0);
    }

    __syncthreads();
    float* red = (float*)SMEM;          // 64x64 f32 (16KB) + 64 L floats
    if (kh == 1) {
#pragma unroll
        for (int qt = 0; qt < 2; ++qt)
#pragma unroll
            for (int reg = 0; reg < 4; ++reg) {
                const int qlx = qrow0 + (qt << 4) + (g << 2) + reg;
#pragma unroll
                for (int dt = 0; dt < 4; ++dt)
                    red[qlx * 64 + (dt << 4) + n] = O[qt][dt][reg];
                if (n == 0) red[4096 + qlx] = L[qt][reg];
            }
    }
    __syncthreads();
    if (kh == 0) {
#pragma unroll
        for (int qt = 0; qt < 2; ++qt)
#pragma unroll
            for (int reg = 0; reg < 4; ++reg) {
                const int qlx = qrow0 + (qt << 4) + (g << 2) + reg;
                const float Ltot = L[qt][reg] + red[4096 + qlx];
                if (mono) {
                    const float inv = 1.0f / Ltot;
                    const size_t row = (size_t)b * NT + qr0 + qlx;
#pragma unroll
                    for (int dt = 0; dt < 4; ++dt)
                        outb[row * NC + col + (dt << 4) + n] =
                            (__bf16)((O[qt][dt][reg] + red[qlx * 64 + (dt << 4) + n]) * inv);
                } else {
                    if (n == 0) Lpart[(size_t)pid * 64 + qlx] = Ltot;
#pragma unroll
                    for (int dt = 0; dt < 4; ++dt)
                        Opart[(size_t)pid * 4096 + qlx * 64 + (dt << 4) + n] =
                            O[qt][dt][reg] + red[qlx * 64 + (dt << 4) + n];
                }
            }
    }
}

// ---------------------------------------------------------------------------
// combine: per (b,h,64-row qtile), out = (sum_p O_p) / (sum_p L_p), bf16
// ---------------------------------------------------------------------------
__global__ __launch_bounds__(256) void combine_kernel(
    const float* __restrict__ Opart, const float* __restrict__ Lpart,
    __bf16* __restrict__ outb)
{
    const int gid = blockIdx.x;              // bh*64 + m
    const int m   = gid & 63, bh = gid >> 6;
    const int b   = bh >> 3, h = bh & 7;
    const int a   = m >> 4;
    const int np  = a + 1;
    const int pbase = bh * 160 + 8 * a * (a + 1) + (m & 15) * np;

    const int tid = threadIdx.x;
    const int c   = (tid & 15) << 2;
    const int rb  = tid >> 4;                // 0..15
#pragma unroll
    for (int pass = 0; pass < 4; ++pass) {
        const int r = rb + (pass << 4);      // 0..63
        float Ls = 0.f;
        f32x4 acc = {0.f, 0.f, 0.f, 0.f};
        for (int p = 0; p < np; ++p) {
            Ls += Lpart[(size_t)(pbase + p) * 64 + r];
            const f32x4 v = *(const f32x4*)&Opart[(size_t)(pbase + p) * 4096 + (r << 6) + c];
            acc += v;
        }
        const float inv = 1.0f / Ls;
        bf16x4 o;
        o[0] = (__bf16)(acc[0] * inv); o[1] = (__bf16)(acc[1] * inv);
        o[2] = (__bf16)(acc[2] * inv); o[3] = (__bf16)(acc[3] * inv);
        *(bf16x4*)&outb[((size_t)b * NT + (m << 6) + r) * NC + h * ND + c] = o;
    }
}

// ---------------------------------------------------------------------------
extern "C" void kernel_launch(void* const* d_in, const int* in_sizes, int n_in,
                              void* d_out, int out_size, void* d_ws, size_t ws_size,
                              hipStream_t stream)
{
    const float* x     = (const float*)d_in[0];
    const float* Wqkv  = (const float*)d_in[1];
    const float* bqkv  = (const float*)d_in[2];
    const float* Wproj = (const float*)d_in[3];
    const float* bproj = (const float*)d_in[4];
    float* out = (float*)d_out;

    // workspace carve (bytes)
    char* ws = (char*)d_ws;
    __bf16* xb     = (__bf16*)(ws);                    //  8.0 MB
    __bf16* qkvb   = (__bf16*)(ws + 8388608);          // 24.0 MB
    __bf16* attb   = (__bf16*)(ws + 33554432);         //  8.0 MB
    __bf16* wqkvt  = (__bf16*)(ws + 41943040);         //  1.5 MB
    __bf16* wprojt = (__bf16*)(ws + 43515904);         //  0.5 MB
    float*  Opart  = (float*)(ws + 44040192);          // 40.0 MB (2560 x 16KB)
    float*  Lpart  = (float*)(ws + 85983232);          // 0.625 MB (2560 x 256B)
    const size_t SPLIT_NEED = 86638592;

    cvt_bf16_kernel<<<dim3(2048), dim3(256), 0, stream>>>(x, xb, NB * NT * NC);
    prep_kernel<<<dim3(256), dim3(256), 0, stream>>>(Wqkv, Wproj, wqkvt, wprojt);

    gemm_glds_kernel<128><<<dim3(N3C / 128, (NB * NT) / 128), dim3(256), 0, stream>>>(
        xb, wqkvt, bqkv, qkvb, NB * NT, N3C, NC, 1);

    if (ws_size >= SPLIT_NEED) {
        attn_kernel<<<dim3(160, NB * NH), dim3(256), 0, stream>>>(
            qkvb, 0, attb, Opart, Lpart);
        combine_kernel<<<dim3(1024), dim3(256), 0, stream>>>(Opart, Lpart, attb);
    } else {
        attn_kernel<<<dim3(64, NB * NH), dim3(256), 0, stream>>>(
            qkvb, 1, attb, (float*)nullptr, (float*)nullptr);
    }

    gemm_glds_kernel<64><<<dim3(NC / 128, (NB * NT) / 64), dim3(256), 0, stream>>>(
        attb, wprojt, bproj, out, NB * NT, NC, NC, 0);
}

// Round 9
// 205.705 us; speedup vs baseline: 1.0031x; 1.0031x over previous
//
#include <hip/hip_runtime.h>
#include <math.h>

#define NB 2
#define NT 4096
#define NC 512
#define NH 8
#define ND 64
#define N3C (3*NC)

typedef __attribute__((ext_vector_type(8))) __bf16 bf16x8;
typedef __attribute__((ext_vector_type(4))) __bf16 bf16x4;
typedef __attribute__((ext_vector_type(4))) float  f32x4;

// async 16B/lane global->LDS DMA; lds base must be wave-uniform
__device__ __forceinline__ void load_lds16(const __bf16* g, __bf16* l) {
    __builtin_amdgcn_global_load_lds(
        (const __attribute__((address_space(1))) void*)g,
        (__attribute__((address_space(3))) void*)l, 16, 0, 0);
}

// 2^x via native v_exp_f32 (gfx950 exp is base-2)
__device__ __forceinline__ float exp2_fast(float x) {
    return __builtin_amdgcn_exp2f(x);
}

// ---------------------------------------------------------------------------
// fp32 -> bf16 elementwise (x)
// ---------------------------------------------------------------------------
__global__ __launch_bounds__(256) void cvt_bf16_kernel(
    const float* __restrict__ x, __bf16* __restrict__ xb, int n)
{
    const int i = (blockIdx.x * 256 + threadIdx.x) << 3;
    if (i < n) {
        float4 a = *(const float4*)(x + i);
        float4 b = *(const float4*)(x + i + 4);
        bf16x8 o;
        o[0] = (__bf16)a.x; o[1] = (__bf16)a.y; o[2] = (__bf16)a.z; o[3] = (__bf16)a.w;
        o[4] = (__bf16)b.x; o[5] = (__bf16)b.y; o[6] = (__bf16)b.z; o[7] = (__bf16)b.w;
        *(bf16x8*)(xb + i) = o;
    }
}

// ---------------------------------------------------------------------------
// prep: W[K][N] fp32 -> Wt[N][K] bf16, both weights in one launch
// ---------------------------------------------------------------------------
__global__ __launch_bounds__(256) void prep_kernel(
    const float* __restrict__ Wqkv, const float* __restrict__ Wproj,
    __bf16* __restrict__ wqkvt, __bf16* __restrict__ wprojt)
{
    __shared__ float T[64][65];
    int id = blockIdx.x;
    const float* W; __bf16* Wt; int N, n0, k0;
    if (id < 192) { W = Wqkv;  Wt = wqkvt;  N = N3C; n0 = (id % 24) << 6; k0 = (id / 24) << 6; }
    else { id -= 192; W = Wproj; Wt = wprojt; N = NC;  n0 = (id & 7) << 6;  k0 = (id >> 3) << 6; }
    const int K = NC;

    const int tx = threadIdx.x & 15, ty = threadIdx.x >> 4;
#pragma unroll
    for (int i = 0; i < 4; ++i) {
        const int r = ty + (i << 4);
        float4 v = *(const float4*)(W + (size_t)(k0 + r) * N + n0 + (tx << 2));
        T[r][(tx << 2) + 0] = v.x;
        T[r][(tx << 2) + 1] = v.y;
        T[r][(tx << 2) + 2] = v.z;
        T[r][(tx << 2) + 3] = v.w;
    }
    __syncthreads();
#pragma unroll
    for (int i = 0; i < 4; ++i) {
        const int nr = ty + (i << 4);
        bf16x4 o;
        o[0] = (__bf16)T[(tx << 2) + 0][nr];
        o[1] = (__bf16)T[(tx << 2) + 1][nr];
        o[2] = (__bf16)T[(tx << 2) + 2][nr];
        o[3] = (__bf16)T[(tx << 2) + 3][nr];
        *(bf16x4*)(Wt + (size_t)(n0 + nr) * K + k0 + (tx << 2)) = o;
    }
}

// ---------------------------------------------------------------------------
// bf16 MFMA GEMM with global_load_lds staging. C = A @ Bt^T + bias.
// ---------------------------------------------------------------------------
template<int BM>
__global__ __launch_bounds__(256) void gemm_glds_kernel(
    const __bf16* __restrict__ A, const __bf16* __restrict__ Bt,
    const float* __restrict__ bias, void* __restrict__ Cout,
    int M, int N, int K, int out_bf16)
{
    constexpr int IT = BM / 32;              // i-tiles per wave (4 or 2)
    constexpr int AI = BM / 32;              // A DMA instrs per wave (4 or 2)
    __shared__ __align__(16) __bf16 As[BM * 64];
    __shared__ __align__(16) __bf16 Bs[128 * 64];

    const int tid  = threadIdx.x;
    const int w    = tid >> 6, lane = tid & 63;
    const int g    = lane >> 4, n = lane & 15;
    const int n7   = n & 7;
    const int wr   = (w >> 1) * (BM / 2);
    const int wc   = (w & 1) << 6;
    const int m0   = blockIdx.y * BM, n0 = blockIdx.x << 7;

    const __bf16* ag[AI]; __bf16* al[AI];
#pragma unroll
    for (int q = 0; q < AI; ++q) {
        const int G = w * (BM * 2) + q * 64 + lane;
        const int r = G >> 3, pg = G & 7, kg = pg ^ (r & 7);
        ag[q] = A + (size_t)(m0 + r) * K + (kg << 3);
        al[q] = As + ((w * (BM * 2) + q * 64) << 3);
    }
    const __bf16* bg[4]; __bf16* bl[4];
#pragma unroll
    for (int q = 0; q < 4; ++q) {
        const int G = w * 256 + q * 64 + lane;
        const int r = G >> 3, pg = G & 7, kg = pg ^ (r & 7);
        bg[q] = Bt + (size_t)(n0 + r) * K + (kg << 3);
        bl[q] = Bs + ((w * 256 + q * 64) << 3);
    }

    f32x4 acc[IT][4];
#pragma unroll
    for (int i = 0; i < IT; ++i)
#pragma unroll
        for (int j = 0; j < 4; ++j) acc[i][j] = (f32x4){0.f, 0.f, 0.f, 0.f};

    const int ksteps = K >> 6;
    for (int ks = 0; ks < ksteps; ++ks) {
        __syncthreads();
        const int ko = ks << 6;
#pragma unroll
        for (int q = 0; q < AI; ++q) load_lds16(ag[q] + ko, al[q]);
#pragma unroll
        for (int q = 0; q < 4;  ++q) load_lds16(bg[q] + ko, bl[q]);
        __syncthreads();

#pragma unroll
        for (int s = 0; s < 2; ++s) {
            bf16x8 af[IT], bf[4];
#pragma unroll
            for (int i = 0; i < IT; ++i) {
                const int row = wr + (i << 4) + n;
                af[i] = *(const bf16x8*)&As[(row << 6) + ((((s << 2) + g) ^ n7) << 3)];
            }
#pragma unroll
            for (int j = 0; j < 4; ++j) {
                const int row = wc + (j << 4) + n;
                bf[j] = *(const bf16x8*)&Bs[(row << 6) + ((((s << 2) + g) ^ n7) << 3)];
            }
#pragma unroll
            for (int i = 0; i < IT; ++i)
#pragma unroll
                for (int j = 0; j < 4; ++j)
                    acc[i][j] = __builtin_amdgcn_mfma_f32_16x16x32_bf16(af[i], bf[j], acc[i][j], 0, 0, 0);
        }
    }

#pragma unroll
    for (int j = 0; j < 4; ++j) {
        const int colg = n0 + wc + (j << 4) + n;
        const float bb = bias[colg];
#pragma unroll
        for (int i = 0; i < IT; ++i) {
#pragma unroll
            for (int reg = 0; reg < 4; ++reg) {
                const int rowg = m0 + wr + (i << 4) + (g << 2) + reg;
                const float v = acc[i][j][reg] + bb;
                if (out_bf16)
                    ((__bf16*)Cout)[(size_t)rowg * N + colg] = (__bf16)v;
                else
                    ((float*)Cout)[(size_t)rowg * N + colg] = v;
            }
        }
    }
}

// ---------------------------------------------------------------------------
// Causal flash attention, 4-wave blocks, 64-row Q tiles, mono.
// R8 vs R4-passing: (a) original (un-swapped) QK^T and original P LDS path —
// the in-register-P family is retired after two unexplainable NaNs; (b) K is
// now staged via global_load_lds into a double-buffered LINEAR [64][64] tile
// with the GEMM-proven XOR-swizzled-source pattern (DMA issued after the
// post-stage barrier -> K[jt+1] load overlaps tile jt's full compute; the
// next tile's __syncthreads vmcnt(0) drain makes it visible). Removes
// 2 ds_write_b128 + 2 global->reg loads per thread-tile. Frag-read banks:
// bank = 4*(g^(n&7))+e -> 2 lanes/bank = free (m136). (c) exp2 fold: Q scale
// = 0.125*log2(e), P = exp2(S') via native v_exp — kills 16 v_mul/thread-tile.
// ---------------------------------------------------------------------------
__global__ __launch_bounds__(256, 4) void attn_kernel(
    const __bf16* __restrict__ qkv, __bf16* __restrict__ out)
{
    __shared__ __align__(16) unsigned char SMEM[34816];
    __bf16 (*QPs)[72] = (__bf16(*)[72])SMEM;                 //  9216 B
    __bf16* Ks        = (__bf16*)(SMEM + 9216);              // 2 x 64x64 linear (16384 B)
    __bf16 (*Vt)[72]  = (__bf16(*)[72])(SMEM + 25600);       //  9216 B

    const int tid  = threadIdx.x;
    const int xi   = blockIdx.x;
    const int bh   = blockIdx.y;
    const int b    = bh >> 3, h = bh & 7;
    const int m    = (bh < 8) ? (63 - xi) : xi;
    const int jt1  = m + 1;

    const int qr0  = m << 6;
    const size_t base = (size_t)b * NT * N3C;
    const int col  = h * ND;

    const int w    = tid >> 6;          // 0..3
    const int lane = tid & 63;
    const int g    = lane >> 4;
    const int n    = lane & 15;
    const int qg   = w >> 1;            // 2 q-groups of 32 rows
    const int kh   = w & 1;             // 2 k-halves of 32 cols
    const int qrow0 = qg << 5;
    const int kcol0 = kh << 5;
    const int sw   = (g ^ (n >> 2)) << 3;

    const int kr = tid >> 3;            // 0..31
    const int kc = (tid & 7) << 3;
    const int vd = lane;                // 0..63 (d index)
    const int vk = w << 3;              // 8 k-rows per wave

    // K DMA descriptors: 2 instrs/thread cover the 64x64 tile; XOR-swizzle
    // folded into the per-lane GLOBAL address (rule #21: linear dest +
    // inverse-swz source + swz on read).
    const __bf16* kg_src[2]; __bf16* kl_dst[2];
#pragma unroll
    for (int q = 0; q < 2; ++q) {
        const int G = w * 128 + q * 64 + lane;       // granule id, 512 total
        const int r = G >> 3, pg = G & 7, kgr = pg ^ (r & 7);
        kg_src[q] = qkv + base + NC + col + (size_t)r * N3C + (kgr << 3);
        kl_dst[q] = Ks + ((w * 128 + q * 64) << 3);  // wave-uniform base
    }
    const __bf16* vptr = qkv + base + 2 * NC + col + vd;

    // Q load + scale: 1/sqrt(64) * log2(e) folded (P computed via exp2)
#pragma unroll
    for (int i = 0; i < 2; ++i) {
        const int r = kr + (i << 5);
        bf16x8 v = *(const bf16x8*)(qkv + base + (size_t)(qr0 + r) * N3C + col + kc);
        bf16x8 q;
#pragma unroll
        for (int j = 0; j < 8; ++j) q[j] = (__bf16)(0.18033688f * (float)v[j]);
        *(bf16x8*)&QPs[r][kc] = q;
    }

    // prologue: issue K[0] DMA (drained by the Q barrier) + V[0] prefetch
#pragma unroll
    for (int q = 0; q < 2; ++q) load_lds16(kg_src[q], kl_dst[q]);
    __bf16 vreg[16];
#pragma unroll
    for (int j = 0; j < 8; ++j) {
        vreg[j]     = vptr[(size_t)(vk + j) * N3C];
        vreg[8 + j] = vptr[(size_t)(vk + 32 + j) * N3C];
    }
    __syncthreads();

    bf16x8 qf[2][2];
#pragma unroll
    for (int qt = 0; qt < 2; ++qt)
#pragma unroll
        for (int hh = 0; hh < 2; ++hh)
            qf[qt][hh] = *(const bf16x8*)&QPs[qrow0 + (qt << 4) + n][(hh << 5) + (g << 3)];

    bf16x8 ones;
#pragma unroll
    for (int j = 0; j < 8; ++j) ones[j] = (__bf16)1.0f;

    f32x4 O[2][4];
#pragma unroll
    for (int qt = 0; qt < 2; ++qt)
#pragma unroll
        for (int dt = 0; dt < 4; ++dt) O[qt][dt] = (f32x4){0.f, 0.f, 0.f, 0.f};
    f32x4 L[2] = {{0.f,0.f,0.f,0.f},{0.f,0.f,0.f,0.f}};

    for (int jt = 0; jt < jt1; ++jt) {
        __syncthreads();                 // prev compute done; K[jt] DMA drained
        {
            bf16x8 va, vb;
#pragma unroll
            for (int j = 0; j < 8; ++j) { va[j] = vreg[j]; vb[j] = vreg[8 + j]; }
            *(bf16x8*)&Vt[vd][vk]      = va;
            *(bf16x8*)&Vt[vd][vk + 32] = vb;
        }
        __syncthreads();                 // V visible

        if (jt + 1 < jt1) {
            // K[jt+1] DMA: overlaps this tile's compute; next barrier drains
            const size_t roff = (size_t)((jt + 1) << 6) * N3C;
            const int bo = ((jt + 1) & 1) << 12;     // 4096-elem buffer offset
#pragma unroll
            for (int q = 0; q < 2; ++q) load_lds16(kg_src[q] + roff, kl_dst[q] + bo);
            const int kr1 = (jt + 1) << 6;
#pragma unroll
            for (int j = 0; j < 8; ++j) {
                vreg[j]     = vptr[(size_t)(kr1 + vk + j) * N3C];
                vreg[8 + j] = vptr[(size_t)(kr1 + vk + 32 + j) * N3C];
            }
        }

        const __bf16* kb = Ks + ((jt & 1) << 12);
        f32x4 S[2][2];
        __builtin_amdgcn_s_setprio(1);
#pragma unroll
        for (int t = 0; t < 2; ++t) {
            const int row = kcol0 + (t << 4) + n;
            const int r7  = row & 7;
            const bf16x8 k0 = *(const bf16x8*)&kb[(row << 6) + ((g ^ r7) << 3)];
            const bf16x8 k1 = *(const bf16x8*)&kb[(row << 6) + (((g ^ 4) ^ r7) << 3)];
#pragma unroll
            for (int qt = 0; qt < 2; ++qt) {
                f32x4 a = {0.f, 0.f, 0.f, 0.f};
                a = __builtin_amdgcn_mfma_f32_16x16x32_bf16(qf[qt][0], k0, a, 0, 0, 0);
                a = __builtin_amdgcn_mfma_f32_16x16x32_bf16(qf[qt][1], k1, a, 0, 0, 0);
                S[qt][t] = a;
            }
        }
        __builtin_amdgcn_s_setprio(0);

        if (jt == m) {   // diagonal tile: causal mask (original layout)
#pragma unroll
            for (int qt = 0; qt < 2; ++qt)
#pragma unroll
                for (int t = 0; t < 2; ++t)
#pragma unroll
                    for (int reg = 0; reg < 4; ++reg) {
                        const int kg  = (jt << 6) + kcol0 + (t << 4) + n;
                        const int qgl = qr0 + qrow0 + (qt << 4) + (g << 2) + reg;
                        if (kg > qgl) S[qt][t][reg] = -INFINITY;
                    }
        }

#pragma unroll
        for (int qt = 0; qt < 2; ++qt)
#pragma unroll
            for (int t = 0; t < 2; ++t)
#pragma unroll
                for (int reg = 0; reg < 4; ++reg)
                    QPs[qrow0 + (qt << 4) + (g << 2) + reg]
                       [kcol0 + (((t << 4) + n) ^ (g << 3))] =
                        (__bf16)exp2_fast(S[qt][t][reg]);

        bf16x8 vf[4];
#pragma unroll
        for (int dt = 0; dt < 4; ++dt) {
            const int vr = (dt << 4) + n;
            vf[dt] = *(const bf16x8*)&Vt[vr][kcol0 + (g << 3)];
        }

        __builtin_amdgcn_s_setprio(1);
#pragma unroll
        for (int qt = 0; qt < 2; ++qt) {
            const bf16x8 p = *(const bf16x8*)&QPs[qrow0 + (qt << 4) + n][kcol0 + sw];
            L[qt] = __builtin_amdgcn_mfma_f32_16x16x32_bf16(p, ones, L[qt], 0, 0, 0);
#pragma unroll
            for (int dt = 0; dt < 4; ++dt)
                O[qt][dt] = __builtin_amdgcn_mfma_f32_16x16x32_bf16(p, vf[dt], O[qt][dt], 0, 0, 0);
        }
        __builtin_amdgcn_s_setprio(0);
    }

    __syncthreads();
    float* red = (float*)SMEM;          // 64x64 f32 (16KB) + 64 L floats
    if (kh == 1) {
#pragma unroll
        for (int qt = 0; qt < 2; ++qt)
#pragma unroll
            for (int reg = 0; reg < 4; ++reg) {
                const int qlx = qrow0 + (qt << 4) + (g << 2) + reg;
#pragma unroll
                for (int dt = 0; dt < 4; ++dt)
                    red[qlx * 64 + (dt << 4) + n] = O[qt][dt][reg];
                if (n == 0) red[4096 + qlx] = L[qt][reg];
            }
    }
    __syncthreads();
    if (kh == 0) {
#pragma unroll
        for (int qt = 0; qt < 2; ++qt)
#pragma unroll
            for (int reg = 0; reg < 4; ++reg) {
                const int qlx = qrow0 + (qt << 4) + (g << 2) + reg;
                const float inv = 1.0f / (L[qt][reg] + red[4096 + qlx]);
                const size_t row = (size_t)b * NT + qr0 + qlx;
#pragma unroll
                for (int dt = 0; dt < 4; ++dt)
                    out[row * NC + col + (dt << 4) + n] =
                        (__bf16)((O[qt][dt][reg] + red[qlx * 64 + (dt << 4) + n]) * inv);
            }
    }
}

// ---------------------------------------------------------------------------
extern "C" void kernel_launch(void* const* d_in, const int* in_sizes, int n_in,
                              void* d_out, int out_size, void* d_ws, size_t ws_size,
                              hipStream_t stream)
{
    const float* x     = (const float*)d_in[0];
    const float* Wqkv  = (const float*)d_in[1];
    const float* bqkv  = (const float*)d_in[2];
    const float* Wproj = (const float*)d_in[3];
    const float* bproj = (const float*)d_in[4];
    float* out = (float*)d_out;

    // workspace carve (bytes)
    char* ws = (char*)d_ws;
    __bf16* xb     = (__bf16*)(ws);                    //  8.0 MB
    __bf16* qkvb   = (__bf16*)(ws + 8388608);          // 24.0 MB
    __bf16* attb   = (__bf16*)(ws + 33554432);         //  8.0 MB
    __bf16* wqkvt  = (__bf16*)(ws + 41943040);         //  1.5 MB
    __bf16* wprojt = (__bf16*)(ws + 43515904);         //  0.5 MB

    cvt_bf16_kernel<<<dim3(2048), dim3(256), 0, stream>>>(x, xb, NB * NT * NC);
    prep_kernel<<<dim3(256), dim3(256), 0, stream>>>(Wqkv, Wproj, wqkvt, wprojt);

    gemm_glds_kernel<128><<<dim3(N3C / 128, (NB * NT) / 128), dim3(256), 0, stream>>>(
        xb, wqkvt, bqkv, qkvb, NB * NT, N3C, NC, 1);

    attn_kernel<<<dim3(64, NB * NH), dim3(256), 0, stream>>>(qkvb, attb);

    gemm_glds_kernel<64><<<dim3(NC / 128, (NB * NT) / 64), dim3(256), 0, stream>>>(
        attb, wprojt, bproj, out, NB * NT, NC, NC, 0);
}

// Round 10
// 200.045 us; speedup vs baseline: 1.0315x; 1.0283x over previous
//
#include <hip/hip_runtime.h>
#include <math.h>

#define NB 2
#define NT 4096
#define NC 512
#define NH 8
#define ND 64
#define N3C (3*NC)

typedef __attribute__((ext_vector_type(8))) __bf16 bf16x8;
typedef __attribute__((ext_vector_type(4))) __bf16 bf16x4;
typedef __attribute__((ext_vector_type(4))) float  f32x4;

// async 16B/lane global->LDS DMA; lds base must be wave-uniform
__device__ __forceinline__ void load_lds16(const __bf16* g, __bf16* l) {
    __builtin_amdgcn_global_load_lds(
        (const __attribute__((address_space(1))) void*)g,
        (__attribute__((address_space(3))) void*)l, 16, 0, 0);
}

// 2^x via native v_exp_f32 (gfx950 exp is base-2)
__device__ __forceinline__ float exp2_fast(float x) {
    return __builtin_amdgcn_exp2f(x);
}

// ---------------------------------------------------------------------------
// fp32 -> bf16 elementwise (x)
// ---------------------------------------------------------------------------
__global__ __launch_bounds__(256) void cvt_bf16_kernel(
    const float* __restrict__ x, __bf16* __restrict__ xb, int n)
{
    const int i = (blockIdx.x * 256 + threadIdx.x) << 3;
    if (i < n) {
        float4 a = *(const float4*)(x + i);
        float4 b = *(const float4*)(x + i + 4);
        bf16x8 o;
        o[0] = (__bf16)a.x; o[1] = (__bf16)a.y; o[2] = (__bf16)a.z; o[3] = (__bf16)a.w;
        o[4] = (__bf16)b.x; o[5] = (__bf16)b.y; o[6] = (__bf16)b.z; o[7] = (__bf16)b.w;
        *(bf16x8*)(xb + i) = o;
    }
}

// ---------------------------------------------------------------------------
// prep: W[K][N] fp32 -> Wt[N][K] bf16, both weights in one launch
// ---------------------------------------------------------------------------
__global__ __launch_bounds__(256) void prep_kernel(
    const float* __restrict__ Wqkv, const float* __restrict__ Wproj,
    __bf16* __restrict__ wqkvt, __bf16* __restrict__ wprojt)
{
    __shared__ float T[64][65];
    int id = blockIdx.x;
    const float* W; __bf16* Wt; int N, n0, k0;
    if (id < 192) { W = Wqkv;  Wt = wqkvt;  N = N3C; n0 = (id % 24) << 6; k0 = (id / 24) << 6; }
    else { id -= 192; W = Wproj; Wt = wprojt; N = NC;  n0 = (id & 7) << 6;  k0 = (id >> 3) << 6; }
    const int K = NC;

    const int tx = threadIdx.x & 15, ty = threadIdx.x >> 4;
#pragma unroll
    for (int i = 0; i < 4; ++i) {
        const int r = ty + (i << 4);
        float4 v = *(const float4*)(W + (size_t)(k0 + r) * N + n0 + (tx << 2));
        T[r][(tx << 2) + 0] = v.x;
        T[r][(tx << 2) + 1] = v.y;
        T[r][(tx << 2) + 2] = v.z;
        T[r][(tx << 2) + 3] = v.w;
    }
    __syncthreads();
#pragma unroll
    for (int i = 0; i < 4; ++i) {
        const int nr = ty + (i << 4);
        bf16x4 o;
        o[0] = (__bf16)T[(tx << 2) + 0][nr];
        o[1] = (__bf16)T[(tx << 2) + 1][nr];
        o[2] = (__bf16)T[(tx << 2) + 2][nr];
        o[3] = (__bf16)T[(tx << 2) + 3][nr];
        *(bf16x4*)(Wt + (size_t)(n0 + nr) * K + k0 + (tx << 2)) = o;
    }
}

// ---------------------------------------------------------------------------
// bf16 MFMA GEMM, 2-phase double-buffered K-loop (R10).
// vs R9: (a) LDS double-buffered; stage[k+1] DMA issued BEFORE compute[k],
// ONE __syncthreads per step (its vmcnt(0) drain completes the in-flight
// stage) -> staging latency hides under MFMA. At K=512 there are only 8
// steps, so the old 2-barrier structure exposed ~400cy L2/L3 latency per
// step. (b) XCD-chunked bijective blockIdx swizzle (T1): each XCD gets
// contiguous same-row blocks -> A-slab reused 12x in its private L2, B
// L2-resident. MFMA order identical -> bit-identical results.
// ---------------------------------------------------------------------------
template<int BM>
__global__ __launch_bounds__(256) void gemm_db_kernel(
    const __bf16* __restrict__ A, const __bf16* __restrict__ Bt,
    const float* __restrict__ bias, void* __restrict__ Cout,
    int M, int N, int K, int out_bf16)
{
    constexpr int IT  = BM / 32;             // i-tiles per wave (4 or 2)
    constexpr int AI  = BM / 32;             // A DMA instrs per wave (4 or 2)
    constexpr int ASZ = BM * 64;             // elems per A buffer
    constexpr int BSZ = 128 * 64;
    __shared__ __align__(16) __bf16 As[2][ASZ];
    __shared__ __align__(16) __bf16 Bs[2][BSZ];

    const int tid  = threadIdx.x;
    const int w    = tid >> 6, lane = tid & 63;
    const int g    = lane >> 4, n = lane & 15;
    const int n7   = n & 15 & 7;
    const int wr   = (w >> 1) * (BM / 2);
    const int wc   = (w & 1) << 6;

    // XCD-chunked bijective swizzle (nwg % 8 == 0 for both instances)
    const int nwgx = gridDim.x;
    const int nwg  = nwgx * gridDim.y;
    const int flat = blockIdx.y * nwgx + blockIdx.x;
    const int s    = (flat & 7) * (nwg >> 3) + (flat >> 3);
    const int m0   = (s / nwgx) * BM, n0 = (s % nwgx) << 7;

    const __bf16* ag[AI]; __bf16* al[AI];
#pragma unroll
    for (int q = 0; q < AI; ++q) {
        const int G = w * (BM * 2) + q * 64 + lane;
        const int r = G >> 3, pg = G & 7, kg = pg ^ (r & 7);
        ag[q] = A + (size_t)(m0 + r) * K + (kg << 3);
        al[q] = &As[0][0] + ((w * (BM * 2) + q * 64) << 3);
    }
    const __bf16* bg[4]; __bf16* bl[4];
#pragma unroll
    for (int q = 0; q < 4; ++q) {
        const int G = w * 256 + q * 64 + lane;
        const int r = G >> 3, pg = G & 7, kg = pg ^ (r & 7);
        bg[q] = Bt + (size_t)(n0 + r) * K + (kg << 3);
        bl[q] = &Bs[0][0] + ((w * 256 + q * 64) << 3);
    }

    f32x4 acc[IT][4];
#pragma unroll
    for (int i = 0; i < IT; ++i)
#pragma unroll
        for (int j = 0; j < 4; ++j) acc[i][j] = (f32x4){0.f, 0.f, 0.f, 0.f};

    // prologue: stage K-step 0 into buffer 0
#pragma unroll
    for (int q = 0; q < AI; ++q) load_lds16(ag[q], al[q]);
#pragma unroll
    for (int q = 0; q < 4;  ++q) load_lds16(bg[q], bl[q]);
    __syncthreads();                         // vmcnt(0) drain -> buf0 ready

    const int ksteps = K >> 6;
    int buf = 0;
    for (int ks = 0; ks < ksteps; ++ks) {
        if (ks + 1 < ksteps) {               // stage next step into other buffer
            const int ko = (ks + 1) << 6;
#pragma unroll
            for (int q = 0; q < AI; ++q) load_lds16(ag[q] + ko, al[q] + (buf ^ 1) * ASZ);
#pragma unroll
            for (int q = 0; q < 4;  ++q) load_lds16(bg[q] + ko, bl[q] + (buf ^ 1) * BSZ);
        }

        const __bf16* Ab = &As[0][0] + buf * ASZ;
        const __bf16* Bb = &Bs[0][0] + buf * BSZ;
#pragma unroll
        for (int sph = 0; sph < 2; ++sph) {
            bf16x8 af[IT], bf[4];
#pragma unroll
            for (int i = 0; i < IT; ++i) {
                const int row = wr + (i << 4) + n;
                af[i] = *(const bf16x8*)&Ab[(row << 6) + ((((sph << 2) + g) ^ n7) << 3)];
            }
#pragma unroll
            for (int j = 0; j < 4; ++j) {
                const int row = wc + (j << 4) + n;
                bf[j] = *(const bf16x8*)&Bb[(row << 6) + ((((sph << 2) + g) ^ n7) << 3)];
            }
#pragma unroll
            for (int i = 0; i < IT; ++i)
#pragma unroll
                for (int j = 0; j < 4; ++j)
                    acc[i][j] = __builtin_amdgcn_mfma_f32_16x16x32_bf16(af[i], bf[j], acc[i][j], 0, 0, 0);
        }

        __syncthreads();     // readers of buf done; vmcnt(0) -> buf^1 complete
        buf ^= 1;
    }

#pragma unroll
    for (int j = 0; j < 4; ++j) {
        const int colg = n0 + wc + (j << 4) + n;
        const float bb = bias[colg];
#pragma unroll
        for (int i = 0; i < IT; ++i) {
#pragma unroll
            for (int reg = 0; reg < 4; ++reg) {
                const int rowg = m0 + wr + (i << 4) + (g << 2) + reg;
                const float v = acc[i][j][reg] + bb;
                if (out_bf16)
                    ((__bf16*)Cout)[(size_t)rowg * N + colg] = (__bf16)v;
                else
                    ((float*)Cout)[(size_t)rowg * N + colg] = v;
            }
        }
    }
}

// ---------------------------------------------------------------------------
// Causal flash attention, 4-wave blocks, 64-row Q tiles, mono (R9, passing).
// ---------------------------------------------------------------------------
__global__ __launch_bounds__(256, 4) void attn_kernel(
    const __bf16* __restrict__ qkv, __bf16* __restrict__ out)
{
    __shared__ __align__(16) unsigned char SMEM[34816];
    __bf16 (*QPs)[72] = (__bf16(*)[72])SMEM;                 //  9216 B
    __bf16* Ks        = (__bf16*)(SMEM + 9216);              // 2 x 64x64 linear (16384 B)
    __bf16 (*Vt)[72]  = (__bf16(*)[72])(SMEM + 25600);       //  9216 B

    const int tid  = threadIdx.x;
    const int xi   = blockIdx.x;
    const int bh   = blockIdx.y;
    const int b    = bh >> 3, h = bh & 7;
    const int m    = (bh < 8) ? (63 - xi) : xi;
    const int jt1  = m + 1;

    const int qr0  = m << 6;
    const size_t base = (size_t)b * NT * N3C;
    const int col  = h * ND;

    const int w    = tid >> 6;          // 0..3
    const int lane = tid & 63;
    const int g    = lane >> 4;
    const int n    = lane & 15;
    const int qg   = w >> 1;            // 2 q-groups of 32 rows
    const int kh   = w & 1;             // 2 k-halves of 32 cols
    const int qrow0 = qg << 5;
    const int kcol0 = kh << 5;
    const int sw   = (g ^ (n >> 2)) << 3;

    const int kr = tid >> 3;            // 0..31
    const int kc = (tid & 7) << 3;
    const int vd = lane;                // 0..63 (d index)
    const int vk = w << 3;              // 8 k-rows per wave

    // K DMA descriptors: XOR-swizzle folded into the per-lane GLOBAL address
    const __bf16* kg_src[2]; __bf16* kl_dst[2];
#pragma unroll
    for (int q = 0; q < 2; ++q) {
        const int G = w * 128 + q * 64 + lane;       // granule id, 512 total
        const int r = G >> 3, pg = G & 7, kgr = pg ^ (r & 7);
        kg_src[q] = qkv + base + NC + col + (size_t)r * N3C + (kgr << 3);
        kl_dst[q] = Ks + ((w * 128 + q * 64) << 3);  // wave-uniform base
    }
    const __bf16* vptr = qkv + base + 2 * NC + col + vd;

    // Q load + scale: 1/sqrt(64) * log2(e) folded (P computed via exp2)
#pragma unroll
    for (int i = 0; i < 2; ++i) {
        const int r = kr + (i << 5);
        bf16x8 v = *(const bf16x8*)(qkv + base + (size_t)(qr0 + r) * N3C + col + kc);
        bf16x8 q;
#pragma unroll
        for (int j = 0; j < 8; ++j) q[j] = (__bf16)(0.18033688f * (float)v[j]);
        *(bf16x8*)&QPs[r][kc] = q;
    }

    // prologue: issue K[0] DMA (drained by the Q barrier) + V[0] prefetch
#pragma unroll
    for (int q = 0; q < 2; ++q) load_lds16(kg_src[q], kl_dst[q]);
    __bf16 vreg[16];
#pragma unroll
    for (int j = 0; j < 8; ++j) {
        vreg[j]     = vptr[(size_t)(vk + j) * N3C];
        vreg[8 + j] = vptr[(size_t)(vk + 32 + j) * N3C];
    }
    __syncthreads();

    bf16x8 qf[2][2];
#pragma unroll
    for (int qt = 0; qt < 2; ++qt)
#pragma unroll
        for (int hh = 0; hh < 2; ++hh)
            qf[qt][hh] = *(const bf16x8*)&QPs[qrow0 + (qt << 4) + n][(hh << 5) + (g << 3)];

    bf16x8 ones;
#pragma unroll
    for (int j = 0; j < 8; ++j) ones[j] = (__bf16)1.0f;

    f32x4 O[2][4];
#pragma unroll
    for (int qt = 0; qt < 2; ++qt)
#pragma unroll
        for (int dt = 0; dt < 4; ++dt) O[qt][dt] = (f32x4){0.f, 0.f, 0.f, 0.f};
    f32x4 L[2] = {{0.f,0.f,0.f,0.f},{0.f,0.f,0.f,0.f}};

    for (int jt = 0; jt < jt1; ++jt) {
        __syncthreads();                 // prev compute done; K[jt] DMA drained
        {
            bf16x8 va, vb;
#pragma unroll
            for (int j = 0; j < 8; ++j) { va[j] = vreg[j]; vb[j] = vreg[8 + j]; }
            *(bf16x8*)&Vt[vd][vk]      = va;
            *(bf16x8*)&Vt[vd][vk + 32] = vb;
        }
        __syncthreads();                 // V visible

        if (jt + 1 < jt1) {
            // K[jt+1] DMA: overlaps this tile's compute; next barrier drains
            const size_t roff = (size_t)((jt + 1) << 6) * N3C;
            const int bo = ((jt + 1) & 1) << 12;     // 4096-elem buffer offset
#pragma unroll
            for (int q = 0; q < 2; ++q) load_lds16(kg_src[q] + roff, kl_dst[q] + bo);
            const int kr1 = (jt + 1) << 6;
#pragma unroll
            for (int j = 0; j < 8; ++j) {
                vreg[j]     = vptr[(size_t)(kr1 + vk + j) * N3C];
                vreg[8 + j] = vptr[(size_t)(kr1 + vk + 32 + j) * N3C];
            }
        }

        const __bf16* kb = Ks + ((jt & 1) << 12);
        f32x4 S[2][2];
        __builtin_amdgcn_s_setprio(1);
#pragma unroll
        for (int t = 0; t < 2; ++t) {
            const int row = kcol0 + (t << 4) + n;
            const int r7  = row & 7;
            const bf16x8 k0 = *(const bf16x8*)&kb[(row << 6) + ((g ^ r7) << 3)];
            const bf16x8 k1 = *(const bf16x8*)&kb[(row << 6) + (((g ^ 4) ^ r7) << 3)];
#pragma unroll
            for (int qt = 0; qt < 2; ++qt) {
                f32x4 a = {0.f, 0.f, 0.f, 0.f};
                a = __builtin_amdgcn_mfma_f32_16x16x32_bf16(qf[qt][0], k0, a, 0, 0, 0);
                a = __builtin_amdgcn_mfma_f32_16x16x32_bf16(qf[qt][1], k1, a, 0, 0, 0);
                S[qt][t] = a;
            }
        }
        __builtin_amdgcn_s_setprio(0);

        if (jt == m) {   // diagonal tile: causal mask
#pragma unroll
            for (int qt = 0; qt < 2; ++qt)
#pragma unroll
                for (int t = 0; t < 2; ++t)
#pragma unroll
                    for (int reg = 0; reg < 4; ++reg) {
                        const int kg  = (jt << 6) + kcol0 + (t << 4) + n;
                        const int qgl = qr0 + qrow0 + (qt << 4) + (g << 2) + reg;
                        if (kg > qgl) S[qt][t][reg] = -INFINITY;
                    }
        }

#pragma unroll
        for (int qt = 0; qt < 2; ++qt)
#pragma unroll
            for (int t = 0; t < 2; ++t)
#pragma unroll
                for (int reg = 0; reg < 4; ++reg)
                    QPs[qrow0 + (qt << 4) + (g << 2) + reg]
                       [kcol0 + (((t << 4) + n) ^ (g << 3))] =
                        (__bf16)exp2_fast(S[qt][t][reg]);

        bf16x8 vf[4];
#pragma unroll
        for (int dt = 0; dt < 4; ++dt) {
            const int vr = (dt << 4) + n;
            vf[dt] = *(const bf16x8*)&Vt[vr][kcol0 + (g << 3)];
        }

        __builtin_amdgcn_s_setprio(1);
#pragma unroll
        for (int qt = 0; qt < 2; ++qt) {
            const bf16x8 p = *(const bf16x8*)&QPs[qrow0 + (qt << 4) + n][kcol0 + sw];
            L[qt] = __builtin_amdgcn_mfma_f32_16x16x32_bf16(p, ones, L[qt], 0, 0, 0);
#pragma unroll
            for (int dt = 0; dt < 4; ++dt)
                O[qt][dt] = __builtin_amdgcn_mfma_f32_16x16x32_bf16(p, vf[dt], O[qt][dt], 0, 0, 0);
        }
        __builtin_amdgcn_s_setprio(0);
    }

    __syncthreads();
    float* red = (float*)SMEM;          // 64x64 f32 (16KB) + 64 L floats
    if (kh == 1) {
#pragma unroll
        for (int qt = 0; qt < 2; ++qt)
#pragma unroll
            for (int reg = 0; reg < 4; ++reg) {
                const int qlx = qrow0 + (qt << 4) + (g << 2) + reg;
#pragma unroll
                for (int dt = 0; dt < 4; ++dt)
                    red[qlx * 64 + (dt << 4) + n] = O[qt][dt][reg];
                if (n == 0) red[4096 + qlx] = L[qt][reg];
            }
    }
    __syncthreads();
    if (kh == 0) {
#pragma unroll
        for (int qt = 0; qt < 2; ++qt)
#pragma unroll
            for (int reg = 0; reg < 4; ++reg) {
                const int qlx = qrow0 + (qt << 4) + (g << 2) + reg;
                const float inv = 1.0f / (L[qt][reg] + red[4096 + qlx]);
                const size_t row = (size_t)b * NT + qr0 + qlx;
#pragma unroll
                for (int dt = 0; dt < 4; ++dt)
                    out[row * NC + col + (dt << 4) + n] =
                        (__bf16)((O[qt][dt][reg] + red[qlx * 64 + (dt << 4) + n]) * inv);
            }
    }
}

// ---------------------------------------------------------------------------
extern "C" void kernel_launch(void* const* d_in, const int* in_sizes, int n_in,
                              void* d_out, int out_size, void* d_ws, size_t ws_size,
                              hipStream_t stream)
{
    const float* x     = (const float*)d_in[0];
    const float* Wqkv  = (const float*)d_in[1];
    const float* bqkv  = (const float*)d_in[2];
    const float* Wproj = (const float*)d_in[3];
    const float* bproj = (const float*)d_in[4];
    float* out = (float*)d_out;

    // workspace carve (bytes)
    char* ws = (char*)d_ws;
    __bf16* xb     = (__bf16*)(ws);                    //  8.0 MB
    __bf16* qkvb   = (__bf16*)(ws + 8388608);          // 24.0 MB
    __bf16* attb   = (__bf16*)(ws + 33554432);         //  8.0 MB
    __bf16* wqkvt  = (__bf16*)(ws + 41943040);         //  1.5 MB
    __bf16* wprojt = (__bf16*)(ws + 43515904);         //  0.5 MB

    cvt_bf16_kernel<<<dim3(2048), dim3(256), 0, stream>>>(x, xb, NB * NT * NC);
    prep_kernel<<<dim3(256), dim3(256), 0, stream>>>(Wqkv, Wproj, wqkvt, wprojt);

    gemm_db_kernel<128><<<dim3(N3C / 128, (NB * NT) / 128), dim3(256), 0, stream>>>(
        xb, wqkvt, bqkv, qkvb, NB * NT, N3C, NC, 1);

    attn_kernel<<<dim3(64, NB * NH), dim3(256), 0, stream>>>(qkvb, attb);

    gemm_db_kernel<64><<<dim3(NC / 128, (NB * NT) / 64), dim3(256), 0, stream>>>(
        attb, wprojt, bproj, out, NB * NT, NC, NC, 0);
}